// Round 1
// 1283.203 us; speedup vs baseline: 1.0559x; 1.0559x over previous
//
// TrigonometryUpdate — MI355X round 2.
// Changes vs r1:
//  * k_out rewritten: parallel LN (4 thr/row, reg-staged), XOR-swizzled Als
//    (kills the 8.4M-cycle 16-way bank conflict), swapped-operand MFMA so the
//    epilogue does float4 stores / ushort4 g-loads. LDS 49.6->16.4 KB.
//  * k_einsum: XCD-aware 1-D grid decode — each XCD owns 16 channels, the 16
//    tiles of a channel dispatch consecutively on that XCD (L2 panel reuse).
//  * k_proj_g: swapped-operand MFMA -> ushort4 stores (was 64 scalar stores).
#include <hip/hip_runtime.h>
#include <stdint.h>

#define NN 512
#define EE 256
#define CC 128
#define NEDGE 16384
#define RR (NN*NN)            // 262144 positions
#define RT3 (RR + 2*NEDGE)    // LN'd rows: z + efeat1 + efeat2

using bf16x8 = __attribute__((ext_vector_type(8))) short;
using f32x4  = __attribute__((ext_vector_type(4))) float;

__device__ __forceinline__ unsigned short f2bf(float f) {
  union { float f; unsigned u; } v; v.f = f;
  unsigned r = v.u + 0x7FFFu + ((v.u >> 16) & 1u);
  return (unsigned short)(r >> 16);
}
__device__ __forceinline__ float bf2f(unsigned short h) {
  union { unsigned u; float f; } v; v.u = ((unsigned)h) << 16;
  return v.f;
}
__device__ __forceinline__ float sigm(float x) { return 1.f / (1.f + __expf(-x)); }

// ---------------- LN over E for z, efeat1, efeat2 -> zl bf16 [RT3][256] ------
__global__ __launch_bounds__(256) void k_ln(
    const float* __restrict__ z, const float* __restrict__ e1,
    const float* __restrict__ e2, const float* __restrict__ lnw,
    const float* __restrict__ lnb, unsigned short* __restrict__ zl) {
  int row = blockIdx.x * 4 + (threadIdx.x >> 6);
  int lane = threadIdx.x & 63;
  const float* src;
  if (row < RR)            src = z  + (size_t)row * EE;
  else if (row < RR+NEDGE) src = e1 + (size_t)(row - RR) * EE;
  else                     src = e2 + (size_t)(row - RR - NEDGE) * EE;
  float4 v = ((const float4*)src)[lane];
  float s = v.x + v.y + v.z + v.w;
  float q = v.x*v.x + v.y*v.y + v.z*v.z + v.w*v.w;
  #pragma unroll
  for (int o = 32; o > 0; o >>= 1) { s += __shfl_xor(s, o); q += __shfl_xor(q, o); }
  float m = s * (1.f/EE);
  float rstd = rsqrtf(q*(1.f/EE) - m*m + 1e-5f);
  float4 wv = ((const float4*)lnw)[lane];
  float4 bv = ((const float4*)lnb)[lane];
  ushort4 o4;
  o4.x = f2bf((v.x - m)*rstd*wv.x + bv.x);
  o4.y = f2bf((v.y - m)*rstd*wv.y + bv.y);
  o4.z = f2bf((v.z - m)*rstd*wv.z + bv.z);
  o4.w = f2bf((v.w - m)*rstd*wv.w + bv.w);
  ((ushort4*)(zl + (size_t)row * EE))[lane] = o4;
}

// ---------------- weights fp32 -> bf16 packs --------------------------------
__global__ __launch_bounds__(256) void k_wconv(
    const float* __restrict__ gl1, const float* __restrict__ l1,
    const float* __restrict__ gl2, const float* __restrict__ l2,
    const float* __restrict__ eg,  const float* __restrict__ las,
    unsigned short* __restrict__ Wcol, unsigned short* __restrict__ Wrow,
    unsigned short* __restrict__ Wlas) {
  int t = blockIdx.x * 256 + threadIdx.x;   // 229376 total
  if (t < 65536) {
    Wcol[t] = f2bf(t < 32768 ? gl1[t] : l1[t - 32768]);
  } else if (t < 196608) {
    int u = t - 65536;
    float v = (u < 32768) ? gl2[u] : (u < 65536) ? l2[u - 32768] : eg[u - 65536];
    Wrow[u] = f2bf(v);
  } else {
    int u = t - 196608;
    Wlas[u] = f2bf(las[u]);
  }
}

// ---------------- paired gate projection (sigmoid(xGt+gb)*(xLt+lb)) ---------
__global__ __launch_bounds__(256) void k_proj_gate(
    const unsigned short* __restrict__ zl, const unsigned short* __restrict__ W,
    const float* __restrict__ gb, const float* __restrict__ lb,
    unsigned short* __restrict__ abOut, float* __restrict__ Pf,
    const int* __restrict__ edges, int mode) {
  __shared__ __attribute__((aligned(16))) short As[128*32];
  __shared__ __attribute__((aligned(16))) short Bg[128*32];
  __shared__ __attribute__((aligned(16))) short Bl[128*32];
  const int t = threadIdx.x, w = t >> 6, lane = t & 63;
  const int mt = blockIdx.x;
  const bool isE = (mt >= RR/128);
  size_t abase; int astride;
  if (!isE) {
    if (mode == 0) { int rt0 = mt*128; abase = (size_t)(rt0 & 511)*512 + (rt0 >> 9); astride = 512; }
    else           { abase = (size_t)mt*128; astride = 1; }
  } else {
    abase = (size_t)RR + (mode ? NEDGE : 0) + (mt*128 - RR); astride = 1;
  }
  const f32x4 z4 = {0.f, 0.f, 0.f, 0.f};
  f32x4 ag[4][4], al[4][4];
  #pragma unroll
  for (int a = 0; a < 4; ++a)
    #pragma unroll
    for (int b = 0; b < 4; ++b) { ag[a][b] = z4; al[a][b] = z4; }
  const int wr = (w >> 1)*64, wc = (w & 1)*64;
  #pragma unroll 1
  for (int kk = 0; kk < 8; ++kk) {
    const int k0 = kk * 32;
    __syncthreads();
    #pragma unroll
    for (int s2 = 0; s2 < 2; ++s2) {
      int sidx = t + s2*256, row = sidx >> 2, seg = sidx & 3;
      int lo = row*32 + seg*8;
      *(uint4*)&As[lo] = *(const uint4*)(zl + (abase + (size_t)row*astride)*EE + k0 + seg*8);
      const unsigned short* wp = W + (size_t)row*EE + k0 + seg*8;
      *(uint4*)&Bg[lo] = *(const uint4*)wp;
      *(uint4*)&Bl[lo] = *(const uint4*)(wp + 128*EE);
    }
    __syncthreads();
    bf16x8 af[4], bgf[4], blf[4];
    #pragma unroll
    for (int f = 0; f < 4; ++f) {
      af[f]  = *(const bf16x8*)&As[(wr + f*16 + (lane & 15))*32 + (lane >> 4)*8];
      bgf[f] = *(const bf16x8*)&Bg[(wc + f*16 + (lane & 15))*32 + (lane >> 4)*8];
      blf[f] = *(const bf16x8*)&Bl[(wc + f*16 + (lane & 15))*32 + (lane >> 4)*8];
    }
    #pragma unroll
    for (int fm = 0; fm < 4; ++fm)
      #pragma unroll
      for (int fn = 0; fn < 4; ++fn) {
        ag[fm][fn] = __builtin_amdgcn_mfma_f32_16x16x32_bf16(af[fm], bgf[fn], ag[fm][fn], 0, 0, 0);
        al[fm][fn] = __builtin_amdgcn_mfma_f32_16x16x32_bf16(af[fm], blf[fn], al[fm][fn], 0, 0, 0);
      }
  }
  const int quad = lane >> 4, lc = lane & 15;
  #pragma unroll
  for (int fm = 0; fm < 4; ++fm)
    #pragma unroll
    for (int fn = 0; fn < 4; ++fn) {
      int c = wc + fn*16 + lc;
      float bgv = gb[c], blv = lb[c];
      float v0 = sigm(ag[fm][fn][0] + bgv) * (al[fm][fn][0] + blv);
      float v1 = sigm(ag[fm][fn][1] + bgv) * (al[fm][fn][1] + blv);
      float v2 = sigm(ag[fm][fn][2] + bgv) * (al[fm][fn][2] + blv);
      float v3 = sigm(ag[fm][fn][3] + bgv) * (al[fm][fn][3] + blv);
      int rl = wr + fm*16 + quad*4;
      if (!isE) {
        size_t rt = (size_t)mt*128 + rl;
        ushort4 o; o.x = f2bf(v0); o.y = f2bf(v1); o.z = f2bf(v2); o.w = f2bf(v3);
        *(ushort4*)&abOut[(size_t)c*RR + rt] = o;
      } else {
        int e0 = mt*128 - RR + rl;
        float vv[4] = {v0, v1, v2, v3};
        #pragma unroll
        for (int rg = 0; rg < 4; ++rg) {
          int e = e0 + rg;
          int i0 = edges[e], i1 = edges[NEDGE + e];
          atomicAdd(&Pf[((size_t)i0*NN + i1)*CC + c], vv[rg]);
        }
      }
    }
}

// ---------------- g = sigmoid(zl @ eg^T + eg_b), z rows only ----------------
// Swapped MFMA operands: lane's 4 acc regs = 4 consecutive e -> ushort4 stores.
__global__ __launch_bounds__(256) void k_proj_g(
    const unsigned short* __restrict__ zl, const unsigned short* __restrict__ Weg,
    const float* __restrict__ egb, unsigned short* __restrict__ gOut) {
  __shared__ __attribute__((aligned(16))) short As[128*32];
  __shared__ __attribute__((aligned(16))) short Bs[128*32];
  const int t = threadIdx.x, w = t >> 6, lane = t & 63;
  const int mt = blockIdx.x, half = blockIdx.y;
  const size_t abase = (size_t)mt * 128;
  const unsigned short* Wb = Weg + (size_t)half * 128 * EE;
  const f32x4 z4 = {0.f, 0.f, 0.f, 0.f};
  f32x4 acc[4][4];                       // [fn(e)][fm(r)]
  #pragma unroll
  for (int a = 0; a < 4; ++a)
    #pragma unroll
    for (int b = 0; b < 4; ++b) acc[a][b] = z4;
  const int wr = (w >> 1)*64, wc = (w & 1)*64;
  #pragma unroll 1
  for (int kk = 0; kk < 8; ++kk) {
    const int k0 = kk * 32;
    __syncthreads();
    #pragma unroll
    for (int s2 = 0; s2 < 2; ++s2) {
      int sidx = t + s2*256, row = sidx >> 2, seg = sidx & 3;
      int lo = row*32 + seg*8;
      *(uint4*)&As[lo] = *(const uint4*)(zl + (abase + row)*EE + k0 + seg*8);
      *(uint4*)&Bs[lo] = *(const uint4*)(Wb + (size_t)row*EE + k0 + seg*8);
    }
    __syncthreads();
    bf16x8 af[4], bf_[4];
    #pragma unroll
    for (int f = 0; f < 4; ++f) {
      af[f]  = *(const bf16x8*)&As[(wr + f*16 + (lane & 15))*32 + (lane >> 4)*8];
      bf_[f] = *(const bf16x8*)&Bs[(wc + f*16 + (lane & 15))*32 + (lane >> 4)*8];
    }
    #pragma unroll
    for (int fn = 0; fn < 4; ++fn)
      #pragma unroll
      for (int fm = 0; fm < 4; ++fm)
        acc[fn][fm] = __builtin_amdgcn_mfma_f32_16x16x32_bf16(bf_[fn], af[fm], acc[fn][fm], 0, 0, 0);
  }
  const int quad = lane >> 4, lc = lane & 15;
  #pragma unroll
  for (int fn = 0; fn < 4; ++fn) {
    int e = half*128 + wc + fn*16 + quad*4;
    float4 bv = *(const float4*)(egb + e);
    #pragma unroll
    for (int fm = 0; fm < 4; ++fm) {
      size_t r = (size_t)mt*128 + wr + fm*16 + lc;
      ushort4 o;
      o.x = f2bf(sigm(acc[fn][fm][0] + bv.x));
      o.y = f2bf(sigm(acc[fn][fm][1] + bv.y));
      o.z = f2bf(sigm(acc[fn][fm][2] + bv.z));
      o.w = f2bf(sigm(acc[fn][fm][3] + bv.w));
      *(ushort4*)&gOut[r*EE + e] = o;
    }
  }
}

// ---------------- P fp32 [pos][c] -> bf16 channel-first [c][pos] ------------
__global__ __launch_bounds__(256) void k_pcvt(
    const float* __restrict__ P1f, const float* __restrict__ P2f,
    unsigned short* __restrict__ P1c, unsigned short* __restrict__ P2c) {
  const float* src = blockIdx.y ? P2f : P1f;
  unsigned short* dst = blockIdx.y ? P2c : P1c;
  __shared__ float Ls[128*65];   // [c][p], pad 65
  const int t = threadIdx.x;
  const size_t pos0 = (size_t)blockIdx.x * 64;
  #pragma unroll
  for (int it = 0; it < 8; ++it) {
    int fi = t + it*256;                 // 2048 float4s
    int p = fi >> 5, cq = fi & 31;
    float4 v = ((const float4*)(src + (pos0 + p)*CC))[cq];
    Ls[(cq*4+0)*65 + p] = v.x; Ls[(cq*4+1)*65 + p] = v.y;
    Ls[(cq*4+2)*65 + p] = v.z; Ls[(cq*4+3)*65 + p] = v.w;
  }
  __syncthreads();
  #pragma unroll
  for (int it = 0; it < 8; ++it) {
    int oi = t + it*256;                 // 2048 ushort4s
    int c = oi >> 4, pq = oi & 15;
    ushort4 o;
    o.x = f2bf(Ls[c*65 + pq*4 + 0]); o.y = f2bf(Ls[c*65 + pq*4 + 1]);
    o.z = f2bf(Ls[c*65 + pq*4 + 2]); o.w = f2bf(Ls[c*65 + pq*4 + 3]);
    *(ushort4*)&dst[(size_t)c*RR + pos0 + pq*4] = o;
  }
}

// ---------------- fused dual einsum: S[c][i*512+j] = P1@ab1 + ab2@P2^T ------
// 1-D grid, XCD-aware decode: XCD x owns channels [x*16, x*16+16); the 16
// spatial tiles of one channel are consecutive on that XCD (panel L2 reuse).
__global__ __launch_bounds__(256) void k_einsum(
    const unsigned short* __restrict__ P1c, const unsigned short* __restrict__ ab1t,
    const unsigned short* __restrict__ ab2c, const unsigned short* __restrict__ P2c,
    float* __restrict__ Sf) {
  __shared__ __attribute__((aligned(16))) short A1s[128*32];
  __shared__ __attribute__((aligned(16))) short B1s[128*32];
  __shared__ __attribute__((aligned(16))) short A2s[128*32];
  __shared__ __attribute__((aligned(16))) short B2s[128*32];
  const int t = threadIdx.x, w = t >> 6, lane = t & 63;
  const int n = blockIdx.x;              // 2048 blocks, 2048 % 8 == 0 (bijective)
  const int xcd = n & 7, bi = n >> 3;    // bi: 0..255
  const int ch = xcd * 16 + (bi >> 4);
  const int tile = bi & 15;
  const int mt = tile & 3, nt = tile >> 2;
  const size_t cb = (size_t)ch * RR;
  const unsigned short* A1g = P1c  + cb + (size_t)mt*128*512;
  const unsigned short* B1g = ab1t + cb + (size_t)nt*128*512;
  const unsigned short* A2g = ab2c + cb + (size_t)mt*128*512;
  const unsigned short* B2g = P2c  + cb + (size_t)nt*128*512;
  const f32x4 z4 = {0.f, 0.f, 0.f, 0.f};
  f32x4 acc[4][4];
  #pragma unroll
  for (int a = 0; a < 4; ++a)
    #pragma unroll
    for (int b = 0; b < 4; ++b) acc[a][b] = z4;
  const int wr = (w >> 1)*64, wc = (w & 1)*64;
  #pragma unroll 1
  for (int kk = 0; kk < 16; ++kk) {
    const int k0 = kk * 32;
    __syncthreads();
    #pragma unroll
    for (int s2 = 0; s2 < 2; ++s2) {
      int sidx = t + s2*256, row = sidx >> 2, seg = sidx & 3;
      int go = row*512 + k0 + seg*8;
      int lo = row*32 + seg*8;
      *(uint4*)&A1s[lo] = *(const uint4*)(A1g + go);
      *(uint4*)&B1s[lo] = *(const uint4*)(B1g + go);
      *(uint4*)&A2s[lo] = *(const uint4*)(A2g + go);
      *(uint4*)&B2s[lo] = *(const uint4*)(B2g + go);
    }
    __syncthreads();
    bf16x8 a1[4], b1[4], a2[4], b2[4];
    #pragma unroll
    for (int f = 0; f < 4; ++f) {
      int ro = (wr + f*16 + (lane & 15))*32 + (lane >> 4)*8;
      int co = (wc + f*16 + (lane & 15))*32 + (lane >> 4)*8;
      a1[f] = *(const bf16x8*)&A1s[ro];
      a2[f] = *(const bf16x8*)&A2s[ro];
      b1[f] = *(const bf16x8*)&B1s[co];
      b2[f] = *(const bf16x8*)&B2s[co];
    }
    #pragma unroll
    for (int fm = 0; fm < 4; ++fm)
      #pragma unroll
      for (int fn = 0; fn < 4; ++fn) {
        acc[fm][fn] = __builtin_amdgcn_mfma_f32_16x16x32_bf16(a1[fm], b1[fn], acc[fm][fn], 0, 0, 0);
        acc[fm][fn] = __builtin_amdgcn_mfma_f32_16x16x32_bf16(a2[fm], b2[fn], acc[fm][fn], 0, 0, 0);
      }
  }
  const int quad = lane >> 4, lc = lane & 15;
  #pragma unroll
  for (int fm = 0; fm < 4; ++fm)
    #pragma unroll
    for (int fn = 0; fn < 4; ++fn) {
      int j = nt*128 + wc + fn*16 + lc;
      int ib = mt*128 + wr + fm*16 + quad*4;
      #pragma unroll
      for (int rg = 0; rg < 4; ++rg)
        Sf[cb + (size_t)(ib + rg)*NN + j] = acc[fm][fn][rg];
    }
}

// ---------------- out = g * (LN_C(S) @ las^T + las_b) -----------------------
// v2: parallel LN (4 thr/row, reg-staged strided loads), XOR-swizzled bf16
// tile (16 KB LDS total), swapped-operand MFMA -> float4 out / ushort4 g.
__global__ __launch_bounds__(256) void k_out(
    const float* __restrict__ Sf, const unsigned short* __restrict__ g,
    const unsigned short* __restrict__ Wlas, const float* __restrict__ lasb,
    const float* __restrict__ lncw, const float* __restrict__ lncb,
    float* __restrict__ out) {
  __shared__ __attribute__((aligned(16))) char Als[64*256];  // [64 rows][128 c] bf16, XOR-swizzled
  const int t = threadIdx.x, w = t >> 6, lane = t & 63;
  const size_t r0 = (size_t)blockIdx.x * 64;
  const int row = t >> 2, part = t & 3;          // 4 threads per row

  // phase 1: each thread loads its row's 32 channels (strided 1 MB apart;
  // 16 lanes of same part -> consecutive rows -> 64 B segments).
  float x[32];
  const float* sp = Sf + (size_t)(part*32)*RR + r0 + row;
  #pragma unroll
  for (int i = 0; i < 32; ++i) x[i] = sp[(size_t)i*RR];
  float s = 0.f, q = 0.f;
  #pragma unroll
  for (int i = 0; i < 32; ++i) { s += x[i]; q += x[i]*x[i]; }
  s += __shfl_xor(s, 1); q += __shfl_xor(q, 1);  // lanes t^1,t^2 share row (row = t>>2)
  s += __shfl_xor(s, 2); q += __shfl_xor(q, 2);
  float m = s * (1.f/CC);
  float rstd = rsqrtf(q*(1.f/CC) - m*m + 1e-5f);

  // phase 2: normalize -> swizzled bf16 tile
  {
    const float4* wv4 = (const float4*)(lncw + part*32);
    const float4* bv4 = (const float4*)(lncb + part*32);
    #pragma unroll
    for (int i4 = 0; i4 < 8; ++i4) {
      float4 wv = wv4[i4], bv = bv4[i4];
      ushort4 o;
      o.x = f2bf((x[i4*4+0]-m)*rstd*wv.x + bv.x);
      o.y = f2bf((x[i4*4+1]-m)*rstd*wv.y + bv.y);
      o.z = f2bf((x[i4*4+2]-m)*rstd*wv.z + bv.z);
      o.w = f2bf((x[i4*4+3]-m)*rstd*wv.w + bv.w);
      int boff = (part*64 + i4*8) ^ ((row & 7) << 4);
      *(ushort4*)(Als + row*256 + boff) = o;
    }
  }
  __syncthreads();

  // phase 3: acc[fe][fr] = Wlas-frag x S-frag  (D: e = quad*4+reg, r = lc)
  const int quad = lane >> 4, lc = lane & 15;
  const f32x4 z4 = {0.f, 0.f, 0.f, 0.f};
  f32x4 acc[4][4];
  #pragma unroll
  for (int a = 0; a < 4; ++a)
    #pragma unroll
    for (int b = 0; b < 4; ++b) acc[a][b] = z4;
  #pragma unroll
  for (int kk = 0; kk < 4; ++kk) {
    bf16x8 wf[4], sfr[4];
    #pragma unroll
    for (int f = 0; f < 4; ++f) {
      wf[f]  = *(const bf16x8*)(Wlas + (size_t)(w*64 + f*16 + lc)*CC + kk*32 + quad*8);
      int r = f*16 + lc;
      sfr[f] = *(const bf16x8*)(Als + r*256 + ((kk*64 + quad*16) ^ ((r & 7) << 4)));
    }
    #pragma unroll
    for (int fe = 0; fe < 4; ++fe)
      #pragma unroll
      for (int fr = 0; fr < 4; ++fr)
        acc[fe][fr] = __builtin_amdgcn_mfma_f32_16x16x32_bf16(wf[fe], sfr[fr], acc[fe][fr], 0, 0, 0);
  }

  // phase 4: epilogue — lane's 4 regs are 4 consecutive e -> float4 stores.
  #pragma unroll
  for (int fe = 0; fe < 4; ++fe) {
    const int e0 = w*64 + fe*16 + quad*4;
    const float4 lb = *(const float4*)(lasb + e0);
    #pragma unroll
    for (int fr = 0; fr < 4; ++fr) {
      const size_t r = r0 + fr*16 + lc;
      ushort4 gv = *(const ushort4*)(g + r*EE + e0);
      f32x4 v = acc[fe][fr];
      float4 o;
      o.x = bf2f(gv.x) * (v[0] + lb.x);
      o.y = bf2f(gv.y) * (v[1] + lb.y);
      o.z = bf2f(gv.z) * (v[2] + lb.z);
      o.w = bf2f(gv.w) * (v[3] + lb.w);
      *(float4*)&out[r*EE + e0] = o;
    }
  }
}

// ---------------------------------------------------------------------------
extern "C" void kernel_launch(void* const* d_in, const int* in_sizes, int n_in,
                              void* d_out, int out_size, void* d_ws, size_t ws_size,
                              hipStream_t stream) {
  const float* z    = (const float*)d_in[0];
  const float* ef1  = (const float*)d_in[1];
  const float* ef2  = (const float*)d_in[2];
  const float* lnw  = (const float*)d_in[3];
  const float* lnb  = (const float*)d_in[4];
  const float* lncw = (const float*)d_in[5];
  const float* lncb = (const float*)d_in[6];
  const float* gl1w = (const float*)d_in[7];
  const float* gl1b = (const float*)d_in[8];
  const float* gl2w = (const float*)d_in[9];
  const float* gl2b = (const float*)d_in[10];
  const float* l1w  = (const float*)d_in[11];
  const float* l1b  = (const float*)d_in[12];
  const float* l2w  = (const float*)d_in[13];
  const float* l2b  = (const float*)d_in[14];
  const float* egw  = (const float*)d_in[15];
  const float* egb  = (const float*)d_in[16];
  const float* lasw = (const float*)d_in[17];
  const float* lasb = (const float*)d_in[18];
  const int* edges1 = (const int*)d_in[19];
  const int* edges2 = (const int*)d_in[20];
  float* out = (float*)d_out;

  char* ws = (char*)d_ws;
  unsigned short* zl   = (unsigned short*)(ws);
  unsigned short* P1c  = (unsigned short*)(ws);
  unsigned short* P2c  = (unsigned short*)(ws + 67108864);
  unsigned short* ab1t = (unsigned short*)(ws + 150994944);   // 67.1M bf16 [c][j*512+i]
  unsigned short* ab2c = (unsigned short*)(ws + 218103808);   // 67.1M bf16 [c][i*512+k]
  unsigned short* gbuf = (unsigned short*)(ws + 285212672);   // 134.2M bf16 [r][256]
  float* P1f = (float*)(ws + 419430400);                      // 134.2M fp32 [pos][c]
  float* Sf  = (float*)(ws + 419430400);                      // alias after P1f dead
  float* P2f = (float*)(ws + 553648128);                      // 134.2M fp32 [pos][c]
  unsigned short* Wcol = (unsigned short*)(ws + 687865856);
  unsigned short* Wrow = (unsigned short*)(ws + 687996928);
  unsigned short* Wlas = (unsigned short*)(ws + 688259072);
  // total = 688,324,608 bytes

  hipMemsetAsync(P1f, 0, (size_t)RR*CC*4, stream);
  hipMemsetAsync(P2f, 0, (size_t)RR*CC*4, stream);
  k_wconv<<<896, 256, 0, stream>>>(gl1w, l1w, gl2w, l2w, egw, lasw, Wcol, Wrow, Wlas);
  k_ln<<<RT3/4, 256, 0, stream>>>(z, ef1, ef2, lnw, lnb, zl);
  k_proj_gate<<<2176, 256, 0, stream>>>(zl, Wcol, gl1b, l1b, ab1t, P1f, edges1, 0);
  k_proj_gate<<<2176, 256, 0, stream>>>(zl, Wrow, gl2b, l2b, ab2c, P2f, edges2, 1);
  k_proj_g<<<dim3(2048, 2), 256, 0, stream>>>(zl, Wrow + 256*EE, egb, gbuf);
  k_pcvt<<<dim3(4096, 2), 256, 0, stream>>>(P1f, P2f, P1c, P2c);
  k_einsum<<<2048, 256, 0, stream>>>(P1c, ab1t, ab2c, P2c, Sf);
  k_out<<<4096, 256, 0, stream>>>(Sf, gbuf, Wlas, lasb, lncw, lncb, out);
}

// Round 2
// 1270.873 us; speedup vs baseline: 1.0662x; 1.0097x over previous
//
// TrigonometryUpdate — MI355X round 3.
// Changes vs r2:
//  * k_out v3: Sf staged via cooperative float4 loads -> LDS [r][c] stride-129
//    (replaces 32 scalar strided dword loads/thread); g prefetched into regs at
//    kernel entry (T14 issue-early); LN + swizzled MFMA path unchanged.
//  * k_einsum / k_proj_gate / k_proj_g: LDS staging via global_load_lds
//    width=16 (layout already lane-linear: lds byte = sidx*16) — removes the
//    reg round-trip + address-calc VALU (Common-mistake #1).
//  * k_einsum: swapped-operand MFMA -> epilogue is 16 float4 stores (64B segs)
//    instead of 64 scalar dword stores (same transform verified in k_proj_g).
#include <hip/hip_runtime.h>
#include <stdint.h>

#define NN 512
#define EE 256
#define CC 128
#define NEDGE 16384
#define RR (NN*NN)            // 262144 positions
#define RT3 (RR + 2*NEDGE)    // LN'd rows: z + efeat1 + efeat2

using bf16x8 = __attribute__((ext_vector_type(8))) short;
using f32x4  = __attribute__((ext_vector_type(4))) float;

__device__ __forceinline__ unsigned short f2bf(float f) {
  union { float f; unsigned u; } v; v.f = f;
  unsigned r = v.u + 0x7FFFu + ((v.u >> 16) & 1u);
  return (unsigned short)(r >> 16);
}
__device__ __forceinline__ float bf2f(unsigned short h) {
  union { unsigned u; float f; } v; v.u = ((unsigned)h) << 16;
  return v.f;
}
__device__ __forceinline__ float sigm(float x) { return 1.f / (1.f + __expf(-x)); }

// async global->LDS DMA, 16B per lane. LDS dest must be lane-linear
// (base + lane*16) — all staging loops here satisfy that (byte = sidx*16).
// AS3 pointer from generic via 32-bit truncation (apertures are 4GB-aligned).
__device__ __forceinline__ void async16(const void* gp, void* lp) {
  __builtin_amdgcn_global_load_lds(
      (const __attribute__((address_space(1))) unsigned int*)(uintptr_t)gp,
      (__attribute__((address_space(3))) unsigned int*)(unsigned)(uintptr_t)lp,
      16, 0, 0);
}

// ---------------- LN over E for z, efeat1, efeat2 -> zl bf16 [RT3][256] ------
__global__ __launch_bounds__(256) void k_ln(
    const float* __restrict__ z, const float* __restrict__ e1,
    const float* __restrict__ e2, const float* __restrict__ lnw,
    const float* __restrict__ lnb, unsigned short* __restrict__ zl) {
  int row = blockIdx.x * 4 + (threadIdx.x >> 6);
  int lane = threadIdx.x & 63;
  const float* src;
  if (row < RR)            src = z  + (size_t)row * EE;
  else if (row < RR+NEDGE) src = e1 + (size_t)(row - RR) * EE;
  else                     src = e2 + (size_t)(row - RR - NEDGE) * EE;
  float4 v = ((const float4*)src)[lane];
  float s = v.x + v.y + v.z + v.w;
  float q = v.x*v.x + v.y*v.y + v.z*v.z + v.w*v.w;
  #pragma unroll
  for (int o = 32; o > 0; o >>= 1) { s += __shfl_xor(s, o); q += __shfl_xor(q, o); }
  float m = s * (1.f/EE);
  float rstd = rsqrtf(q*(1.f/EE) - m*m + 1e-5f);
  float4 wv = ((const float4*)lnw)[lane];
  float4 bv = ((const float4*)lnb)[lane];
  ushort4 o4;
  o4.x = f2bf((v.x - m)*rstd*wv.x + bv.x);
  o4.y = f2bf((v.y - m)*rstd*wv.y + bv.y);
  o4.z = f2bf((v.z - m)*rstd*wv.z + bv.z);
  o4.w = f2bf((v.w - m)*rstd*wv.w + bv.w);
  ((ushort4*)(zl + (size_t)row * EE))[lane] = o4;
}

// ---------------- weights fp32 -> bf16 packs --------------------------------
__global__ __launch_bounds__(256) void k_wconv(
    const float* __restrict__ gl1, const float* __restrict__ l1,
    const float* __restrict__ gl2, const float* __restrict__ l2,
    const float* __restrict__ eg,  const float* __restrict__ las,
    unsigned short* __restrict__ Wcol, unsigned short* __restrict__ Wrow,
    unsigned short* __restrict__ Wlas) {
  int t = blockIdx.x * 256 + threadIdx.x;   // 229376 total
  if (t < 65536) {
    Wcol[t] = f2bf(t < 32768 ? gl1[t] : l1[t - 32768]);
  } else if (t < 196608) {
    int u = t - 65536;
    float v = (u < 32768) ? gl2[u] : (u < 65536) ? l2[u - 32768] : eg[u - 65536];
    Wrow[u] = f2bf(v);
  } else {
    int u = t - 196608;
    Wlas[u] = f2bf(las[u]);
  }
}

// ---------------- paired gate projection (sigmoid(xGt+gb)*(xLt+lb)) ---------
__global__ __launch_bounds__(256) void k_proj_gate(
    const unsigned short* __restrict__ zl, const unsigned short* __restrict__ W,
    const float* __restrict__ gb, const float* __restrict__ lb,
    unsigned short* __restrict__ abOut, float* __restrict__ Pf,
    const int* __restrict__ edges, int mode) {
  __shared__ __attribute__((aligned(16))) short As[128*32];
  __shared__ __attribute__((aligned(16))) short Bg[128*32];
  __shared__ __attribute__((aligned(16))) short Bl[128*32];
  const int t = threadIdx.x, w = t >> 6, lane = t & 63;
  const int mt = blockIdx.x;
  const bool isE = (mt >= RR/128);
  size_t abase; int astride;
  if (!isE) {
    if (mode == 0) { int rt0 = mt*128; abase = (size_t)(rt0 & 511)*512 + (rt0 >> 9); astride = 512; }
    else           { abase = (size_t)mt*128; astride = 1; }
  } else {
    abase = (size_t)RR + (mode ? NEDGE : 0) + (mt*128 - RR); astride = 1;
  }
  const f32x4 z4 = {0.f, 0.f, 0.f, 0.f};
  f32x4 ag[4][4], al[4][4];
  #pragma unroll
  for (int a = 0; a < 4; ++a)
    #pragma unroll
    for (int b = 0; b < 4; ++b) { ag[a][b] = z4; al[a][b] = z4; }
  const int wr = (w >> 1)*64, wc = (w & 1)*64;
  #pragma unroll 1
  for (int kk = 0; kk < 8; ++kk) {
    const int k0 = kk * 32;
    __syncthreads();
    #pragma unroll
    for (int s2 = 0; s2 < 2; ++s2) {
      int sidx = t + s2*256, row = sidx >> 2, seg = sidx & 3;
      const unsigned short* ap = zl + (abase + (size_t)row*astride)*EE + k0 + seg*8;
      const unsigned short* wp = W + (size_t)row*EE + k0 + seg*8;
      async16(ap, (char*)As + sidx*16);
      async16(wp, (char*)Bg + sidx*16);
      async16(wp + 128*EE, (char*)Bl + sidx*16);
    }
    __syncthreads();
    bf16x8 af[4], bgf[4], blf[4];
    #pragma unroll
    for (int f = 0; f < 4; ++f) {
      af[f]  = *(const bf16x8*)&As[(wr + f*16 + (lane & 15))*32 + (lane >> 4)*8];
      bgf[f] = *(const bf16x8*)&Bg[(wc + f*16 + (lane & 15))*32 + (lane >> 4)*8];
      blf[f] = *(const bf16x8*)&Bl[(wc + f*16 + (lane & 15))*32 + (lane >> 4)*8];
    }
    #pragma unroll
    for (int fm = 0; fm < 4; ++fm)
      #pragma unroll
      for (int fn = 0; fn < 4; ++fn) {
        ag[fm][fn] = __builtin_amdgcn_mfma_f32_16x16x32_bf16(af[fm], bgf[fn], ag[fm][fn], 0, 0, 0);
        al[fm][fn] = __builtin_amdgcn_mfma_f32_16x16x32_bf16(af[fm], blf[fn], al[fm][fn], 0, 0, 0);
      }
  }
  const int quad = lane >> 4, lc = lane & 15;
  #pragma unroll
  for (int fm = 0; fm < 4; ++fm)
    #pragma unroll
    for (int fn = 0; fn < 4; ++fn) {
      int c = wc + fn*16 + lc;
      float bgv = gb[c], blv = lb[c];
      float v0 = sigm(ag[fm][fn][0] + bgv) * (al[fm][fn][0] + blv);
      float v1 = sigm(ag[fm][fn][1] + bgv) * (al[fm][fn][1] + blv);
      float v2 = sigm(ag[fm][fn][2] + bgv) * (al[fm][fn][2] + blv);
      float v3 = sigm(ag[fm][fn][3] + bgv) * (al[fm][fn][3] + blv);
      int rl = wr + fm*16 + quad*4;
      if (!isE) {
        size_t rt = (size_t)mt*128 + rl;
        ushort4 o; o.x = f2bf(v0); o.y = f2bf(v1); o.z = f2bf(v2); o.w = f2bf(v3);
        *(ushort4*)&abOut[(size_t)c*RR + rt] = o;
      } else {
        int e0 = mt*128 - RR + rl;
        float vv[4] = {v0, v1, v2, v3};
        #pragma unroll
        for (int rg = 0; rg < 4; ++rg) {
          int e = e0 + rg;
          int i0 = edges[e], i1 = edges[NEDGE + e];
          atomicAdd(&Pf[((size_t)i0*NN + i1)*CC + c], vv[rg]);
        }
      }
    }
}

// ---------------- g = sigmoid(zl @ eg^T + eg_b), z rows only ----------------
__global__ __launch_bounds__(256) void k_proj_g(
    const unsigned short* __restrict__ zl, const unsigned short* __restrict__ Weg,
    const float* __restrict__ egb, unsigned short* __restrict__ gOut) {
  __shared__ __attribute__((aligned(16))) short As[128*32];
  __shared__ __attribute__((aligned(16))) short Bs[128*32];
  const int t = threadIdx.x, w = t >> 6, lane = t & 63;
  const int mt = blockIdx.x, half = blockIdx.y;
  const size_t abase = (size_t)mt * 128;
  const unsigned short* Wb = Weg + (size_t)half * 128 * EE;
  const f32x4 z4 = {0.f, 0.f, 0.f, 0.f};
  f32x4 acc[4][4];                       // [fn(e)][fm(r)]
  #pragma unroll
  for (int a = 0; a < 4; ++a)
    #pragma unroll
    for (int b = 0; b < 4; ++b) acc[a][b] = z4;
  const int wr = (w >> 1)*64, wc = (w & 1)*64;
  #pragma unroll 1
  for (int kk = 0; kk < 8; ++kk) {
    const int k0 = kk * 32;
    __syncthreads();
    #pragma unroll
    for (int s2 = 0; s2 < 2; ++s2) {
      int sidx = t + s2*256, row = sidx >> 2, seg = sidx & 3;
      async16(zl + (abase + row)*EE + k0 + seg*8, (char*)As + sidx*16);
      async16(Wb + (size_t)row*EE + k0 + seg*8,   (char*)Bs + sidx*16);
    }
    __syncthreads();
    bf16x8 af[4], bf_[4];
    #pragma unroll
    for (int f = 0; f < 4; ++f) {
      af[f]  = *(const bf16x8*)&As[(wr + f*16 + (lane & 15))*32 + (lane >> 4)*8];
      bf_[f] = *(const bf16x8*)&Bs[(wc + f*16 + (lane & 15))*32 + (lane >> 4)*8];
    }
    #pragma unroll
    for (int fn = 0; fn < 4; ++fn)
      #pragma unroll
      for (int fm = 0; fm < 4; ++fm)
        acc[fn][fm] = __builtin_amdgcn_mfma_f32_16x16x32_bf16(bf_[fn], af[fm], acc[fn][fm], 0, 0, 0);
  }
  const int quad = lane >> 4, lc = lane & 15;
  #pragma unroll
  for (int fn = 0; fn < 4; ++fn) {
    int e = half*128 + wc + fn*16 + quad*4;
    float4 bv = *(const float4*)(egb + e);
    #pragma unroll
    for (int fm = 0; fm < 4; ++fm) {
      size_t r = (size_t)mt*128 + wr + fm*16 + lc;
      ushort4 o;
      o.x = f2bf(sigm(acc[fn][fm][0] + bv.x));
      o.y = f2bf(sigm(acc[fn][fm][1] + bv.y));
      o.z = f2bf(sigm(acc[fn][fm][2] + bv.z));
      o.w = f2bf(sigm(acc[fn][fm][3] + bv.w));
      *(ushort4*)&gOut[r*EE + e] = o;
    }
  }
}

// ---------------- P fp32 [pos][c] -> bf16 channel-first [c][pos] ------------
__global__ __launch_bounds__(256) void k_pcvt(
    const float* __restrict__ P1f, const float* __restrict__ P2f,
    unsigned short* __restrict__ P1c, unsigned short* __restrict__ P2c) {
  const float* src = blockIdx.y ? P2f : P1f;
  unsigned short* dst = blockIdx.y ? P2c : P1c;
  __shared__ float Ls[128*65];   // [c][p], pad 65
  const int t = threadIdx.x;
  const size_t pos0 = (size_t)blockIdx.x * 64;
  #pragma unroll
  for (int it = 0; it < 8; ++it) {
    int fi = t + it*256;                 // 2048 float4s
    int p = fi >> 5, cq = fi & 31;
    float4 v = ((const float4*)(src + (pos0 + p)*CC))[cq];
    Ls[(cq*4+0)*65 + p] = v.x; Ls[(cq*4+1)*65 + p] = v.y;
    Ls[(cq*4+2)*65 + p] = v.z; Ls[(cq*4+3)*65 + p] = v.w;
  }
  __syncthreads();
  #pragma unroll
  for (int it = 0; it < 8; ++it) {
    int oi = t + it*256;                 // 2048 ushort4s
    int c = oi >> 4, pq = oi & 15;
    ushort4 o;
    o.x = f2bf(Ls[c*65 + pq*4 + 0]); o.y = f2bf(Ls[c*65 + pq*4 + 1]);
    o.z = f2bf(Ls[c*65 + pq*4 + 2]); o.w = f2bf(Ls[c*65 + pq*4 + 3]);
    *(ushort4*)&dst[(size_t)c*RR + pos0 + pq*4] = o;
  }
}

// ---------------- fused dual einsum: S[c][i*512+j] = P1@ab1 + ab2@P2^T ------
__global__ __launch_bounds__(256) void k_einsum(
    const unsigned short* __restrict__ P1c, const unsigned short* __restrict__ ab1t,
    const unsigned short* __restrict__ ab2c, const unsigned short* __restrict__ P2c,
    float* __restrict__ Sf) {
  __shared__ __attribute__((aligned(16))) short A1s[128*32];
  __shared__ __attribute__((aligned(16))) short B1s[128*32];
  __shared__ __attribute__((aligned(16))) short A2s[128*32];
  __shared__ __attribute__((aligned(16))) short B2s[128*32];
  const int t = threadIdx.x, w = t >> 6, lane = t & 63;
  const int n = blockIdx.x;              // 2048 blocks, bijective XCD decode
  const int xcd = n & 7, bi = n >> 3;    // bi: 0..255
  const int ch = xcd * 16 + (bi >> 4);
  const int tile = bi & 15;
  const int mt = tile & 3, nt = tile >> 2;
  const size_t cb = (size_t)ch * RR;
  const unsigned short* A1g = P1c  + cb + (size_t)mt*128*512;
  const unsigned short* B1g = ab1t + cb + (size_t)nt*128*512;
  const unsigned short* A2g = ab2c + cb + (size_t)mt*128*512;
  const unsigned short* B2g = P2c  + cb + (size_t)nt*128*512;
  const f32x4 z4 = {0.f, 0.f, 0.f, 0.f};
  f32x4 acc[4][4];                       // [fn(j)][fm(i)] (swapped operands)
  #pragma unroll
  for (int a = 0; a < 4; ++a)
    #pragma unroll
    for (int b = 0; b < 4; ++b) acc[a][b] = z4;
  const int wr = (w >> 1)*64, wc = (w & 1)*64;
  #pragma unroll 1
  for (int kk = 0; kk < 16; ++kk) {
    const int k0 = kk * 32;
    __syncthreads();
    #pragma unroll
    for (int s2 = 0; s2 < 2; ++s2) {
      int sidx = t + s2*256, row = sidx >> 2, seg = sidx & 3;
      int go = row*512 + k0 + seg*8;
      char* lo = (char*)0 + sidx*16;
      async16(A1g + go, (char*)A1s + sidx*16);
      async16(B1g + go, (char*)B1s + sidx*16);
      async16(A2g + go, (char*)A2s + sidx*16);
      async16(B2g + go, (char*)B2s + sidx*16);
      (void)lo;
    }
    __syncthreads();
    bf16x8 a1[4], b1[4], a2[4], b2[4];
    #pragma unroll
    for (int f = 0; f < 4; ++f) {
      int ro = (wr + f*16 + (lane & 15))*32 + (lane >> 4)*8;
      int co = (wc + f*16 + (lane & 15))*32 + (lane >> 4)*8;
      a1[f] = *(const bf16x8*)&A1s[ro];
      a2[f] = *(const bf16x8*)&A2s[ro];
      b1[f] = *(const bf16x8*)&B1s[co];
      b2[f] = *(const bf16x8*)&B2s[co];
    }
    #pragma unroll
    for (int fn = 0; fn < 4; ++fn)
      #pragma unroll
      for (int fm = 0; fm < 4; ++fm) {
        acc[fn][fm] = __builtin_amdgcn_mfma_f32_16x16x32_bf16(b1[fn], a1[fm], acc[fn][fm], 0, 0, 0);
        acc[fn][fm] = __builtin_amdgcn_mfma_f32_16x16x32_bf16(b2[fn], a2[fm], acc[fn][fm], 0, 0, 0);
      }
  }
  // D[row=j-side (quad*4+rg)][col=i-side (lc)] -> float4 stores along j
  const int quad = lane >> 4, lc = lane & 15;
  #pragma unroll
  for (int fn = 0; fn < 4; ++fn)
    #pragma unroll
    for (int fm = 0; fm < 4; ++fm) {
      int jb = nt*128 + wc + fn*16 + quad*4;
      int i  = mt*128 + wr + fm*16 + lc;
      f32x4 v = acc[fn][fm];
      float4 o; o.x = v[0]; o.y = v[1]; o.z = v[2]; o.w = v[3];
      *(float4*)&Sf[cb + (size_t)i*NN + jb] = o;
    }
}

// ---------------- out = g * (LN_C(S) @ las^T + las_b) -----------------------
// v3: g prefetched at entry; Sf staged via float4 -> LDS [r][c] stride 129;
// 4-thread/row LN from LDS; swizzled bf16 tile + swapped-operand MFMA.
__global__ __launch_bounds__(256) void k_out(
    const float* __restrict__ Sf, const unsigned short* __restrict__ g,
    const unsigned short* __restrict__ Wlas, const float* __restrict__ lasb,
    const float* __restrict__ lncw, const float* __restrict__ lncb,
    float* __restrict__ out) {
  __shared__ float Sls[64*129];                              // 33.0 KB fp32 tile
  __shared__ __attribute__((aligned(16))) char Als[64*256];  // 16 KB swizzled bf16
  const int t = threadIdx.x, w = t >> 6, lane = t & 63;
  const int quad = lane >> 4, lc = lane & 15;
  const size_t r0 = (size_t)blockIdx.x * 64;

  // phase 0: issue all g loads now (consumed only in the epilogue) — their
  // HBM/L3 latency hides under staging + LN + MFMA.
  ushort4 gpre[4][4];
  #pragma unroll
  for (int fe = 0; fe < 4; ++fe) {
    const int e0 = w*64 + fe*16 + quad*4;
    #pragma unroll
    for (int fr = 0; fr < 4; ++fr) {
      const size_t r = r0 + fr*16 + lc;
      gpre[fe][fr] = *(const ushort4*)(g + r*EE + e0);
    }
  }

  // phase 1: stage Sf tile (128 ch x 64 r) via float4, transpose into LDS.
  // lanes: 16 r-quads x 4 channels -> 4 x 256B segments per wave-load.
  #pragma unroll
  for (int it = 0; it < 8; ++it) {
    int fi = t + it*256;                 // 2048 float4s
    int c = fi >> 4, rq = fi & 15;
    float4 v = ((const float4*)(Sf + (size_t)c*RR + r0))[rq];
    Sls[(rq*4+0)*129 + c] = v.x; Sls[(rq*4+1)*129 + c] = v.y;
    Sls[(rq*4+2)*129 + c] = v.z; Sls[(rq*4+3)*129 + c] = v.w;
  }
  __syncthreads();

  // phase 2: LN — 4 threads per row, 32 channels each, 2-shuffle reduce.
  const int row = t >> 2, part = t & 3;
  float x[32];
  #pragma unroll
  for (int i = 0; i < 32; ++i) x[i] = Sls[row*129 + part*32 + i];
  float s = 0.f, q = 0.f;
  #pragma unroll
  for (int i = 0; i < 32; ++i) { s += x[i]; q += x[i]*x[i]; }
  s += __shfl_xor(s, 1); q += __shfl_xor(q, 1);
  s += __shfl_xor(s, 2); q += __shfl_xor(q, 2);
  float m = s * (1.f/CC);
  float rstd = rsqrtf(q*(1.f/CC) - m*m + 1e-5f);
  {
    const float4* wv4 = (const float4*)(lncw + part*32);
    const float4* bv4 = (const float4*)(lncb + part*32);
    #pragma unroll
    for (int i4 = 0; i4 < 8; ++i4) {
      float4 wv = wv4[i4], bv = bv4[i4];
      ushort4 o;
      o.x = f2bf((x[i4*4+0]-m)*rstd*wv.x + bv.x);
      o.y = f2bf((x[i4*4+1]-m)*rstd*wv.y + bv.y);
      o.z = f2bf((x[i4*4+2]-m)*rstd*wv.z + bv.z);
      o.w = f2bf((x[i4*4+3]-m)*rstd*wv.w + bv.w);
      int boff = (part*64 + i4*8) ^ ((row & 7) << 4);
      *(ushort4*)(Als + row*256 + boff) = o;
    }
  }
  __syncthreads();

  // phase 3: acc[fe][fr] = Wlas-frag x S-frag  (D: e = quad*4+reg, r = lc)
  const f32x4 z4 = {0.f, 0.f, 0.f, 0.f};
  f32x4 acc[4][4];
  #pragma unroll
  for (int a = 0; a < 4; ++a)
    #pragma unroll
    for (int b = 0; b < 4; ++b) acc[a][b] = z4;
  #pragma unroll
  for (int kk = 0; kk < 4; ++kk) {
    bf16x8 wf[4], sfr[4];
    #pragma unroll
    for (int f = 0; f < 4; ++f) {
      wf[f]  = *(const bf16x8*)(Wlas + (size_t)(w*64 + f*16 + lc)*CC + kk*32 + quad*8);
      int r = f*16 + lc;
      sfr[f] = *(const bf16x8*)(Als + r*256 + ((kk*64 + quad*16) ^ ((r & 7) << 4)));
    }
    #pragma unroll
    for (int fe = 0; fe < 4; ++fe)
      #pragma unroll
      for (int fr = 0; fr < 4; ++fr)
        acc[fe][fr] = __builtin_amdgcn_mfma_f32_16x16x32_bf16(wf[fe], sfr[fr], acc[fe][fr], 0, 0, 0);
  }

  // phase 4: epilogue — float4 stores, prefetched g.
  #pragma unroll
  for (int fe = 0; fe < 4; ++fe) {
    const int e0 = w*64 + fe*16 + quad*4;
    const float4 lb = *(const float4*)(lasb + e0);
    #pragma unroll
    for (int fr = 0; fr < 4; ++fr) {
      const size_t r = r0 + fr*16 + lc;
      ushort4 gv = gpre[fe][fr];
      f32x4 v = acc[fe][fr];
      float4 o;
      o.x = bf2f(gv.x) * (v[0] + lb.x);
      o.y = bf2f(gv.y) * (v[1] + lb.y);
      o.z = bf2f(gv.z) * (v[2] + lb.z);
      o.w = bf2f(gv.w) * (v[3] + lb.w);
      *(float4*)&out[r*EE + e0] = o;
    }
  }
}

// ---------------------------------------------------------------------------
extern "C" void kernel_launch(void* const* d_in, const int* in_sizes, int n_in,
                              void* d_out, int out_size, void* d_ws, size_t ws_size,
                              hipStream_t stream) {
  const float* z    = (const float*)d_in[0];
  const float* ef1  = (const float*)d_in[1];
  const float* ef2  = (const float*)d_in[2];
  const float* lnw  = (const float*)d_in[3];
  const float* lnb  = (const float*)d_in[4];
  const float* lncw = (const float*)d_in[5];
  const float* lncb = (const float*)d_in[6];
  const float* gl1w = (const float*)d_in[7];
  const float* gl1b = (const float*)d_in[8];
  const float* gl2w = (const float*)d_in[9];
  const float* gl2b = (const float*)d_in[10];
  const float* l1w  = (const float*)d_in[11];
  const float* l1b  = (const float*)d_in[12];
  const float* l2w  = (const float*)d_in[13];
  const float* l2b  = (const float*)d_in[14];
  const float* egw  = (const float*)d_in[15];
  const float* egb  = (const float*)d_in[16];
  const float* lasw = (const float*)d_in[17];
  const float* lasb = (const float*)d_in[18];
  const int* edges1 = (const int*)d_in[19];
  const int* edges2 = (const int*)d_in[20];
  float* out = (float*)d_out;

  char* ws = (char*)d_ws;
  unsigned short* zl   = (unsigned short*)(ws);
  unsigned short* P1c  = (unsigned short*)(ws);
  unsigned short* P2c  = (unsigned short*)(ws + 67108864);
  unsigned short* ab1t = (unsigned short*)(ws + 150994944);   // 67.1M bf16 [c][j*512+i]
  unsigned short* ab2c = (unsigned short*)(ws + 218103808);   // 67.1M bf16 [c][i*512+k]
  unsigned short* gbuf = (unsigned short*)(ws + 285212672);   // 134.2M bf16 [r][256]
  float* P1f = (float*)(ws + 419430400);                      // 134.2M fp32 [pos][c]
  float* Sf  = (float*)(ws + 419430400);                      // alias after P1f dead
  float* P2f = (float*)(ws + 553648128);                      // 134.2M fp32 [pos][c]
  unsigned short* Wcol = (unsigned short*)(ws + 687865856);
  unsigned short* Wrow = (unsigned short*)(ws + 687996928);
  unsigned short* Wlas = (unsigned short*)(ws + 688259072);
  // total = 688,324,608 bytes

  hipMemsetAsync(P1f, 0, (size_t)RR*CC*4, stream);
  hipMemsetAsync(P2f, 0, (size_t)RR*CC*4, stream);
  k_wconv<<<896, 256, 0, stream>>>(gl1w, l1w, gl2w, l2w, egw, lasw, Wcol, Wrow, Wlas);
  k_ln<<<RT3/4, 256, 0, stream>>>(z, ef1, ef2, lnw, lnb, zl);
  k_proj_gate<<<2176, 256, 0, stream>>>(zl, Wcol, gl1b, l1b, ab1t, P1f, edges1, 0);
  k_proj_gate<<<2176, 256, 0, stream>>>(zl, Wrow, gl2b, l2b, ab2c, P2f, edges2, 1);
  k_proj_g<<<dim3(2048, 2), 256, 0, stream>>>(zl, Wrow + 256*EE, egb, gbuf);
  k_pcvt<<<dim3(4096, 2), 256, 0, stream>>>(P1f, P2f, P1c, P2c);
  k_einsum<<<2048, 256, 0, stream>>>(P1c, ab1t, ab2c, P2c, Sf);
  k_out<<<4096, 256, 0, stream>>>(Sf, gbuf, Wlas, lasb, lncw, lncb, out);
}